// Round 2
// baseline (47.161 us; speedup 1.0000x reference)
//
#include <hip/hip_runtime.h>

// NODE ensemble fused forward, round 1.
//   logits = x @ fsel^T (bf16 MFMA), p = sigmoid(logits - thr),
//   out[b] = sum_t fold(p_t, leaf_weights_t)
//
// Structure:
//   prep kernel: pack fsel fp32 [384][512] -> bf16 MFMA B-frag layout in d_ws
//   main kernel: block = 256 thr (4 waves), 32 rows; wave = 32 rows x 96 cols;
//                grid = 512 blocks (2/CU). x staged to LDS bf16 once; B-frags
//                direct from L2; no K-loop barriers.

#define DD     512
#define NCOL   384
#define NTREE  64
#define NDEPTH 6
#define BM     32          // rows per block
#define XSTR   520         // bf16 x stride (+8 pad: rows step 4 banks)
#define LSTR   392         // bf16 logits stride (384 + 8 pad)

typedef __bf16 bf16_t;
typedef __bf16 bf16x8 __attribute__((ext_vector_type(8)));
typedef __bf16 bf16x4 __attribute__((ext_vector_type(4)));
typedef float  f32x4  __attribute__((ext_vector_type(4)));

// pk[((cf*16 + ks)*64 + lane)*8 + j] = fsel[cf*16+(lane&15)][ks*32+(lane>>4)*8+j]
__global__ __launch_bounds__(256) void node_pack(const float* __restrict__ fsel,
                                                 bf16_t* __restrict__ pk)
{
  int tid  = blockIdx.x * 256 + threadIdx.x;   // 0..24575
  int lane = tid & 63;
  int ks   = (tid >> 6) & 15;
  int cf   = tid >> 10;                        // 0..23
  int col  = cf * 16 + (lane & 15);
  int k    = ks * 32 + (lane >> 4) * 8;
  float4 f0 = *reinterpret_cast<const float4*>(fsel + (size_t)col * DD + k);
  float4 f1 = *reinterpret_cast<const float4*>(fsel + (size_t)col * DD + k + 4);
  bf16x8 v;
  v[0] = (bf16_t)f0.x; v[1] = (bf16_t)f0.y; v[2] = (bf16_t)f0.z; v[3] = (bf16_t)f0.w;
  v[4] = (bf16_t)f1.x; v[5] = (bf16_t)f1.y; v[6] = (bf16_t)f1.z; v[7] = (bf16_t)f1.w;
  *reinterpret_cast<bf16x8*>(pk + (size_t)tid * 8) = v;
}

__global__ __launch_bounds__(256) void node_main(
    const float*  __restrict__ x,     // [B][512]
    const bf16_t* __restrict__ pk,    // packed B frags
    const float*  __restrict__ thr,   // [384]
    const float*  __restrict__ lw,    // [64][64]
    float*        __restrict__ out)   // [B]
{
  __shared__ alignas(16) char smem[BM * XSTR * 2];   // 33280 B
  bf16_t* xs  = (bf16_t*)smem;                       // [32][XSTR] during GEMM
  bf16_t* lgs = (bf16_t*)smem;                       // [32][LSTR] during epilogue

  const int tid  = threadIdx.x;
  const int lane = tid & 63;
  const int wv   = tid >> 6;          // col-group during GEMM, row-group in epilogue
  const int rowbase = blockIdx.x * BM;
  const int c  = lane & 15;
  const int kg = lane >> 4;

  // ---- stage x (32 rows) fp32 -> bf16 LDS, once ----
  #pragma unroll
  for (int i = 0; i < (BM * DD) / (4 * 256); ++i) {  // 16 iters
    int idx = i * 256 + tid;
    int e   = idx << 2;
    int r   = e >> 9;
    int k   = e & 511;
    float4 f = *reinterpret_cast<const float4*>(x + (size_t)(rowbase + r) * DD + k);
    bf16x4 v;
    v[0] = (bf16_t)f.x; v[1] = (bf16_t)f.y; v[2] = (bf16_t)f.z; v[3] = (bf16_t)f.w;
    *reinterpret_cast<bf16x4*>(xs + r * XSTR + k) = v;
  }
  __syncthreads();

  // ---- GEMM: wave = 32 rows x 96 cols (cf = wv*6 .. wv*6+5), no barriers ----
  f32x4 acc[2][6];
  #pragma unroll
  for (int r = 0; r < 2; ++r)
    #pragma unroll
    for (int f = 0; f < 6; ++f) acc[r][f] = (f32x4){0.f, 0.f, 0.f, 0.f};

  const bf16_t* bbase = pk + (size_t)wv * 6 * 16 * 64 * 8 + (size_t)lane * 8;
  const bf16_t* xa0 = xs + c * XSTR + kg * 8;
  const bf16_t* xa1 = xs + (16 + c) * XSTR + kg * 8;

  #pragma unroll 4
  for (int ks = 0; ks < 16; ++ks) {
    bf16x8 a0 = *reinterpret_cast<const bf16x8*>(xa0 + ks * 32);
    bf16x8 a1 = *reinterpret_cast<const bf16x8*>(xa1 + ks * 32);
    #pragma unroll
    for (int f = 0; f < 6; ++f) {
      bf16x8 b = *reinterpret_cast<const bf16x8*>(bbase + f * 8192 + ks * 512);
      acc[0][f] = __builtin_amdgcn_mfma_f32_16x16x32_bf16(a0, b, acc[0][f], 0, 0, 0);
      acc[1][f] = __builtin_amdgcn_mfma_f32_16x16x32_bf16(a1, b, acc[1][f], 0, 0, 0);
    }
  }

  __syncthreads();   // all waves done with xs

  // ---- transpose logits through LDS (bf16) ----
  // D layout: row = r2*16 + kg*4 + reg, col = wv*96 + f*16 + c
  #pragma unroll
  for (int r2 = 0; r2 < 2; ++r2)
    #pragma unroll
    for (int f = 0; f < 6; ++f)
      #pragma unroll
      for (int reg = 0; reg < 4; ++reg)
        lgs[(r2 * 16 + kg * 4 + reg) * LSTR + wv * 96 + f * 16 + c] =
            (bf16_t)acc[r2][f][reg];
  __syncthreads();

  // ---- epilogue: lane = tree (64), wave wv handles rows wv*8 .. wv*8+7 ----
  const int T = lane;
  float w[64];
  #pragma unroll
  for (int j = 0; j < 16; ++j) {
    float4 f = *reinterpret_cast<const float4*>(lw + (size_t)T * 64 + j * 4);
    w[4*j] = f.x; w[4*j+1] = f.y; w[4*j+2] = f.z; w[4*j+3] = f.w;
  }
  float th[NDEPTH];
  #pragma unroll
  for (int d = 0; d < NDEPTH; ++d) th[d] = thr[T * NDEPTH + d];

  #pragma unroll
  for (int rr = 0; rr < 8; ++rr) {
    const int row = wv * 8 + rr;
    const bf16_t* lrow = lgs + row * LSTR + T * NDEPTH;
    float p[NDEPTH];
    #pragma unroll
    for (int d = 0; d < NDEPTH; ++d) {
      float z = (float)lrow[d] - th[d];
      p[d] = 1.0f / (1.0f + __expf(-z));
    }
    // bottom-up fold: leaf bit (5-d)==0 selects p[d], ==1 selects 1-p[d]
    float v[32];
    #pragma unroll
    for (int j = 0; j < 32; ++j) v[j] = fmaf(p[5], w[2*j] - w[2*j+1], w[2*j+1]);
    #pragma unroll
    for (int j = 0; j < 16; ++j) v[j] = fmaf(p[4], v[2*j] - v[2*j+1], v[2*j+1]);
    #pragma unroll
    for (int j = 0; j < 8;  ++j) v[j] = fmaf(p[3], v[2*j] - v[2*j+1], v[2*j+1]);
    #pragma unroll
    for (int j = 0; j < 4;  ++j) v[j] = fmaf(p[2], v[2*j] - v[2*j+1], v[2*j+1]);
    #pragma unroll
    for (int j = 0; j < 2;  ++j) v[j] = fmaf(p[1], v[2*j] - v[2*j+1], v[2*j+1]);
    float tv = fmaf(p[0], v[0] - v[1], v[1]);

    #pragma unroll
    for (int off = 32; off; off >>= 1) tv += __shfl_xor(tv, off, 64);
    if (lane == 0) out[rowbase + row] = tv;
  }
}

extern "C" void kernel_launch(void* const* d_in, const int* in_sizes, int n_in,
                              void* d_out, int out_size, void* d_ws, size_t ws_size,
                              hipStream_t stream) {
  const float* x    = (const float*)d_in[0];
  const float* fsel = (const float*)d_in[1];
  const float* thr  = (const float*)d_in[2];
  const float* lw   = (const float*)d_in[3];
  float* out = (float*)d_out;
  bf16_t* pk = (bf16_t*)d_ws;                 // 384*512*2 = 393216 B

  const int B = in_sizes[0] / DD;             // 16384

  node_pack<<<dim3(NCOL * DD / 8 / 256), dim3(256), 0, stream>>>(fsel, pk);
  node_main<<<dim3(B / BM), dim3(256), 0, stream>>>(x, pk, thr, lw, out);
}